// Round 9
// baseline (210.231 us; speedup 1.0000x reference)
//
#include <hip/hip_runtime.h>
#include <hip/hip_fp16.h>

#define N_NODES 50000
#define N_EDGES 800000
#define IN_F    128
#define HID_F   64
#define OUT_F   40

#define EPB   4096                          // edges per sort block
#define NBLK  ((N_EDGES + EPB - 1) / EPB)   // 196 sort blocks
#define NBK   ((N_NODES + 255) / 256)       // 196 buckets (dst >> 8)
#define CAP   6144                          // per-bucket LDS cap (avg 4082, sd 64)
#define NREP  32                            // BN-stat atomic replicas
#define NB_MM ((N_NODES + 63) / 64)         // 782 MFMA-GEMM blocks (64 rows each)

typedef _Float16 half8v __attribute__((ext_vector_type(8)));
typedef float    f32x4  __attribute__((ext_vector_type(4)));

union h8cv { uint4 u; __half h[8]; };

// ============ pass 1: per-block bucket sort, block-local output ============

__global__ __launch_bounds__(512) void k_binscatter(const int* __restrict__ ei,
                                                    int* __restrict__ blkcnt,
                                                    unsigned int* __restrict__ bket,
                                                    float* __restrict__ st2) {
    __shared__ int h[256], fill[256], sc[256];
    __shared__ unsigned int staged[EPB];   // 16 KB
    int t = threadIdx.x;
    if (t < 256) h[t] = 0;
    if (blockIdx.x == 0)                   // zero BN-stat replicas once
        for (int i = t; i < NREP * 2 * HID_F; i += 512) st2[i] = 0.f;
    __syncthreads();
    int base = blockIdx.x * EPB;
    int nedge = N_EDGES - base; if (nedge > EPB) nedge = EPB;
#pragma unroll
    for (int it = 0; it < EPB / 512; ++it) {
        int e = base + it * 512 + t;
        if (e < N_EDGES) atomicAdd(&h[ei[N_EDGES + e] >> 8], 1);
    }
    __syncthreads();
    int v = (t < 256) ? h[t] : 0;
    if (t < 256) sc[t] = v;
    __syncthreads();
#pragma unroll
    for (int o = 1; o < 256; o <<= 1) {
        int u = (t < 256 && t >= o) ? sc[t - o] : 0;
        __syncthreads();
        if (t < 256) sc[t] += u;
        __syncthreads();
    }
    if (t < 256) fill[t] = sc[t] - v;      // exclusive
    __syncthreads();
#pragma unroll
    for (int it = 0; it < EPB / 512; ++it) {
        int e = base + it * 512 + t;
        if (e < N_EDGES) {
            int srcv = ei[e], dstv = ei[N_EDGES + e];
            int p = atomicAdd(&fill[dstv >> 8], 1);
            staged[p] = ((unsigned int)dstv << 16) | (unsigned int)srcv;
        }
    }
    __syncthreads();
    for (int i = t; i < nedge; i += 512) bket[base + i] = staged[i];   // coalesced
    if (t < NBK) blkcnt[t * NBLK + blockIdx.x] = h[t];
}

// ============ pass 2: per-bucket CSR build (scans done in-kernel) ============

__global__ __launch_bounds__(512) void k_bucket(const int* __restrict__ blkcnt,
                                                const unsigned int* __restrict__ bket,
                                                int* __restrict__ rowptr,
                                                float* __restrict__ dinv,
                                                unsigned short* __restrict__ ssrc) {
    __shared__ unsigned int keys[CAP];     // 24 KB
    __shared__ unsigned short outb[CAP];   // 12 KB
    __shared__ int colpre[256], rowcnt[256], boffs[256];
    __shared__ int cnt[256], loc[256], fillb[256], sc[256];
    __shared__ int wsum[8], sbase, ssize;
    int b = blockIdx.x, t = threadIdx.x;
    int lane = t & 63, wid = t >> 6;

    int cp = 0, rc = 0;
    if (t < NBLK) {
        for (int bp = 0; bp < b; ++bp) cp += blkcnt[bp * NBLK + t];   // coalesced
        rc = blkcnt[b * NBLK + t];
    }
    if (t < 256) { colpre[t] = cp; rowcnt[t] = rc; }
    int red = cp;
#pragma unroll
    for (int o = 32; o > 0; o >>= 1) red += __shfl_down(red, o);
    if (lane == 0) wsum[wid] = red;
    __syncthreads();
    if (t == 0) {
        int s = 0;
#pragma unroll
        for (int r = 0; r < 8; ++r) s += wsum[r];
        sbase = s;
    }
    if (t < 256) sc[t] = rc;
    __syncthreads();
#pragma unroll
    for (int o = 1; o < 256; o <<= 1) {
        int u = (t < 256 && t >= o) ? sc[t - o] : 0;
        __syncthreads();
        if (t < 256) sc[t] += u;
        __syncthreads();
    }
    if (t < 256) boffs[t] = sc[t] - rc;
    if (t == 255) ssize = sc[255];
    __syncthreads();
    int base = sbase, size = ssize;

    for (int jj = wid; jj < NBLK; jj += 8) {
        int len = rowcnt[jj];
        int gs  = jj * EPB + colpre[jj];
        int d0  = boffs[jj];
        for (int o = lane; o < len; o += 64) keys[d0 + o] = bket[gs + o];
    }
    if (t < 256) cnt[t] = 0;
    __syncthreads();

    for (int i = t; i < size; i += 512) atomicAdd(&cnt[(keys[i] >> 16) & 255], 1);
    __syncthreads();
    int cv = (t < 256) ? cnt[t] : 0;
    if (t < 256) sc[t] = cv;
    __syncthreads();
#pragma unroll
    for (int o = 1; o < 256; o <<= 1) {
        int u = (t < 256 && t >= o) ? sc[t - o] : 0;
        __syncthreads();
        if (t < 256) sc[t] += u;
        __syncthreads();
    }
    if (t < 256) { loc[t] = sc[t] - cv; fillb[t] = sc[t] - cv; }
    int node = b * 256 + t;
    if (t < 256 && node < N_NODES) {
        rowptr[node] = base + loc[t];
        dinv[node]   = rsqrtf((float)cv + 1.0f);   // + self-loop
    }
    if (b == 0 && t == 0) rowptr[N_NODES] = N_EDGES;
    __syncthreads();

    for (int i = t; i < size; i += 512) {
        unsigned int k = keys[i];
        int p = atomicAdd(&fillb[(k >> 16) & 255], 1);
        outb[p] = (unsigned short)(k & 0xFFFFu);
    }
    __syncthreads();
    for (int i = t; i < size; i += 512) ssrc[base + i] = outb[i];
}

// ============ GEMM1 (MFMA): h1s[N,64] = (x @ W1) * dinv, fp16 out ============

__global__ __launch_bounds__(256) void k_gemm1(const float* __restrict__ x,
                                               const float* __restrict__ W1,
                                               const float* __restrict__ dinv,
                                               __half* __restrict__ h1s) {
    __shared__ _Float16 sA[64][IN_F + 8];   // 17408 B
    __shared__ _Float16 sB[64][IN_F + 8];   // 17408 B  (sB[n][k] = W1[k][n])
    int t = threadIdx.x;
    int row0 = blockIdx.x * 64;
    for (int i = t; i < 64 * 32; i += 256) {
        int r  = i >> 5;
        int c4 = i & 31;
        int gr = row0 + r;
        float4 v = make_float4(0.f, 0.f, 0.f, 0.f);
        if (gr < N_NODES) v = ((const float4*)x)[gr * 32 + c4];
        sA[r][c4 * 4 + 0] = (_Float16)v.x;
        sA[r][c4 * 4 + 1] = (_Float16)v.y;
        sA[r][c4 * 4 + 2] = (_Float16)v.z;
        sA[r][c4 * 4 + 3] = (_Float16)v.w;
    }
    for (int i = t; i < IN_F * HID_F; i += 256) {
        int k = i >> 6, n = i & 63;
        sB[n][k] = (_Float16)W1[i];
    }
    __syncthreads();

    int lane = t & 63, wid = t >> 6;
    int quad = lane >> 4, l15 = lane & 15;
    int m0 = wid * 16;
    half8v af[4];
#pragma unroll
    for (int ks = 0; ks < 4; ++ks)
        af[ks] = *(const half8v*)&sA[m0 + l15][ks * 32 + quad * 8];
    f32x4 acc[4];
#pragma unroll
    for (int nt = 0; nt < 4; ++nt) acc[nt] = (f32x4)(0.f);
#pragma unroll
    for (int nt = 0; nt < 4; ++nt) {
#pragma unroll
        for (int ks = 0; ks < 4; ++ks) {
            half8v bf = *(const half8v*)&sB[nt * 16 + l15][ks * 32 + quad * 8];
            acc[nt] = __builtin_amdgcn_mfma_f32_16x16x32_f16(af[ks], bf, acc[nt], 0, 0, 0);
        }
    }
    float dv[4];
    int rbase = row0 + m0 + quad * 4;
#pragma unroll
    for (int r = 0; r < 4; ++r)
        dv[r] = (rbase + r < N_NODES) ? dinv[rbase + r] : 0.f;
#pragma unroll
    for (int nt = 0; nt < 4; ++nt) {
        int col = nt * 16 + l15;
#pragma unroll
        for (int r = 0; r < 4; ++r) {
            int gr = rbase + r;
            if (gr < N_NODES)
                h1s[gr * HID_F + col] = __float2half(acc[nt][r] * dv[r]);
        }
    }
}

// ============ layer-1 aggregation + fused BN statistics ============
// 8 groups x 8 lanes; each group gathers a different neighbor with one
// uint4 (16B) load -> 8 neighbors per load instruction, 32 in flight.

__global__ __launch_bounds__(256) void k_agg1(const int* __restrict__ rowptr,
                                              const unsigned short* __restrict__ ssrc,
                                              const float* __restrict__ dinv,
                                              const __half* __restrict__ h1s,
                                              const float* __restrict__ b1,
                                              __half* __restrict__ agg1h,
                                              float* __restrict__ st2) {
    int lane = threadIdx.x & 63;
    int rloc = threadIdx.x >> 6;
    int g = lane >> 3, i = lane & 7;
    int d = blockIdx.x * 4 + rloc;
    int base = rowptr[d];
    int end  = rowptr[d + 1];
    float acc[8];
#pragma unroll
    for (int c = 0; c < 8; ++c) acc[c] = 0.f;
    for (int j0 = base; j0 < end; j0 += 64) {
        int idx = j0 + lane;
        int sl = (idx < end) ? (int)ssrc[idx] : 0;
        int m = end - j0; if (m > 64) m = 64;
        for (int c0 = 0; c0 < m; c0 += 32) {
            uint4 v[4];
#pragma unroll
            for (int k = 0; k < 4; ++k) {
                int j  = c0 + k * 8 + g;
                int jj = (j < m) ? j : (m - 1);
                int s  = __shfl(sl, jj);
                v[k] = ((const uint4*)(h1s + (size_t)s * HID_F))[i];
            }
#pragma unroll
            for (int k = 0; k < 4; ++k) {
                bool ok = (c0 + k * 8 + g) < m;
                h8cv cv; cv.u = v[k];
#pragma unroll
                for (int c = 0; c < 8; ++c)
                    acc[c] += ok ? __half2float(cv.h[c]) : 0.f;
            }
        }
    }
    // fold the 8 neighbor-groups (lane bits 3..5)
#pragma unroll
    for (int c = 0; c < 8; ++c) {
        acc[c] += __shfl_xor(acc[c], 8);
        acc[c] += __shfl_xor(acc[c], 16);
        acc[c] += __shfl_xor(acc[c], 32);
    }
    // self-loop + norm + bias
    h8cv self; self.u = ((const uint4*)(h1s + (size_t)d * HID_F))[i];
    float di = dinv[d];
    float val[8];
#pragma unroll
    for (int c = 0; c < 8; ++c)
        val[c] = (acc[c] + __half2float(self.h[c])) * di + b1[i * 8 + c];
    if (g == 0) {
        h8cv ov;
#pragma unroll
        for (int c = 0; c < 8; ++c) ov.h[c] = __float2half(val[c]);
        ((uint4*)(agg1h + (size_t)d * HID_F))[i] = ov.u;
    }
    // BN partial sums
    __shared__ float ls[4][HID_F], ls2[4][HID_F];
    if (g == 0) {
#pragma unroll
        for (int c = 0; c < 8; ++c) {
            ls[rloc][i * 8 + c]  = val[c];
            ls2[rloc][i * 8 + c] = val[c] * val[c];
        }
    }
    __syncthreads();
    if (rloc == 0) {
        float sm = ls[0][lane] + ls[1][lane] + ls[2][lane] + ls[3][lane];
        float s2 = ls2[0][lane] + ls2[1][lane] + ls2[2][lane] + ls2[3][lane];
        float* strow = st2 + (blockIdx.x & (NREP - 1)) * (2 * HID_F);
        atomicAdd(&strow[lane], sm);
        atomicAdd(&strow[HID_F + lane], s2);
    }
}

// ============ GEMM2 (MFMA): h2p[N,64] = relu(bn(agg1)) @ W2 * dinv ============
// rows padded 40 -> 64 (cols 40..63 zero) so agg2 can use the 8-group gather.

__global__ __launch_bounds__(256) void k_gemm2(const __half* __restrict__ agg1h,
                                               const float* __restrict__ st2,
                                               const float* __restrict__ gamma,
                                               const float* __restrict__ beta,
                                               const float* __restrict__ W2,
                                               const float* __restrict__ dinv,
                                               __half* __restrict__ h2p) {
    __shared__ _Float16 sA[64][HID_F + 8];   // 9216 B
    __shared__ _Float16 sB[48][HID_F + 8];   // 6912 B  (sB[n][k] = W2[k][n], pad n>=40)
    __shared__ float sScale[HID_F], sShift[HID_F];
    int t = threadIdx.x;
    if (t < HID_F) {
        float sm = 0.f, s2 = 0.f;
#pragma unroll
        for (int r = 0; r < NREP; ++r) {
            sm += st2[r * (2 * HID_F) + t];
            s2 += st2[r * (2 * HID_F) + HID_F + t];
        }
        float mean = sm * (1.0f / N_NODES);
        float var  = s2 * (1.0f / N_NODES) - mean * mean;
        float inv  = rsqrtf(var + 1e-5f);
        float gv   = gamma[t];
        sScale[t]  = gv * inv;
        sShift[t]  = beta[t] - gv * inv * mean;
    }
    for (int i = t; i < 48 * HID_F; i += 256) {
        int k = i / 48, n = i - k * 48;
        sB[n][k] = (n < OUT_F) ? (_Float16)W2[k * OUT_F + n] : (_Float16)0.f;
    }
    __syncthreads();
    int row0 = blockIdx.x * 64;
    for (int i = t; i < 64 * HID_F; i += 256) {
        int r = i >> 6, k = i & 63;
        int gr = row0 + r;
        float v = 0.f;
        if (gr < N_NODES) {
            float a = __half2float(agg1h[gr * HID_F + k]);
            v = fmaxf(a * sScale[k] + sShift[k], 0.f);
        }
        sA[r][k] = (_Float16)v;
    }
    __syncthreads();

    int lane = t & 63, wid = t >> 6;
    int quad = lane >> 4, l15 = lane & 15;
    int m0 = wid * 16;
    half8v af[2];
#pragma unroll
    for (int ks = 0; ks < 2; ++ks)
        af[ks] = *(const half8v*)&sA[m0 + l15][ks * 32 + quad * 8];
    f32x4 acc[3];
#pragma unroll
    for (int nt = 0; nt < 3; ++nt) acc[nt] = (f32x4)(0.f);
#pragma unroll
    for (int nt = 0; nt < 3; ++nt) {
#pragma unroll
        for (int ks = 0; ks < 2; ++ks) {
            half8v bf = *(const half8v*)&sB[nt * 16 + l15][ks * 32 + quad * 8];
            acc[nt] = __builtin_amdgcn_mfma_f32_16x16x32_f16(af[ks], bf, acc[nt], 0, 0, 0);
        }
    }
    float dv[4];
    int rbase = row0 + m0 + quad * 4;
#pragma unroll
    for (int r = 0; r < 4; ++r)
        dv[r] = (rbase + r < N_NODES) ? dinv[rbase + r] : 0.f;
#pragma unroll
    for (int nt = 0; nt < 3; ++nt) {
        int col = nt * 16 + l15;
#pragma unroll
        for (int r = 0; r < 4; ++r) {
            int gr = rbase + r;
            if (gr < N_NODES)
                h2p[(size_t)gr * 64 + col] = __float2half(acc[nt][r] * dv[r]);
        }
    }
#pragma unroll
    for (int r = 0; r < 4; ++r) {          // zero pad cols 48..63
        int gr = rbase + r;
        if (gr < N_NODES) h2p[(size_t)gr * 64 + 48 + l15] = __float2half(0.f);
    }
}

// ============ layer-2 aggregation: 8-group wide gather -> d_out ============

__global__ __launch_bounds__(256) void k_agg2(const int* __restrict__ rowptr,
                                              const unsigned short* __restrict__ ssrc,
                                              const float* __restrict__ dinv,
                                              const __half* __restrict__ h2p,
                                              const float* __restrict__ b2,
                                              float* __restrict__ out) {
    int lane = threadIdx.x & 63;
    int rloc = threadIdx.x >> 6;
    int g = lane >> 3, i = lane & 7;
    int d = blockIdx.x * 4 + rloc;
    int base = rowptr[d];
    int end  = rowptr[d + 1];
    float acc[8];
#pragma unroll
    for (int c = 0; c < 8; ++c) acc[c] = 0.f;
    for (int j0 = base; j0 < end; j0 += 64) {
        int idx = j0 + lane;
        int sl = (idx < end) ? (int)ssrc[idx] : 0;
        int m = end - j0; if (m > 64) m = 64;
        for (int c0 = 0; c0 < m; c0 += 32) {
            uint4 v[4];
#pragma unroll
            for (int k = 0; k < 4; ++k) {
                int j  = c0 + k * 8 + g;
                int jj = (j < m) ? j : (m - 1);
                int s  = __shfl(sl, jj);
                v[k] = ((const uint4*)(h2p + (size_t)s * 64))[i];
            }
#pragma unroll
            for (int k = 0; k < 4; ++k) {
                bool ok = (c0 + k * 8 + g) < m;
                h8cv cv; cv.u = v[k];
#pragma unroll
                for (int c = 0; c < 8; ++c)
                    acc[c] += ok ? __half2float(cv.h[c]) : 0.f;
            }
        }
    }
#pragma unroll
    for (int c = 0; c < 8; ++c) {
        acc[c] += __shfl_xor(acc[c], 8);
        acc[c] += __shfl_xor(acc[c], 16);
        acc[c] += __shfl_xor(acc[c], 32);
    }
    if (g == 0 && i < 5) {                 // cols i*8 .. i*8+7 (<40)
        h8cv self; self.u = ((const uint4*)(h2p + (size_t)d * 64))[i];
        float di = dinv[d];
        const float4 b2a = ((const float4*)b2)[i * 2];
        const float4 b2b = ((const float4*)b2)[i * 2 + 1];
        float4 o0, o1;
        o0.x = (acc[0] + __half2float(self.h[0])) * di + b2a.x;
        o0.y = (acc[1] + __half2float(self.h[1])) * di + b2a.y;
        o0.z = (acc[2] + __half2float(self.h[2])) * di + b2a.z;
        o0.w = (acc[3] + __half2float(self.h[3])) * di + b2a.w;
        o1.x = (acc[4] + __half2float(self.h[4])) * di + b2b.x;
        o1.y = (acc[5] + __half2float(self.h[5])) * di + b2b.y;
        o1.z = (acc[6] + __half2float(self.h[6])) * di + b2b.z;
        o1.w = (acc[7] + __half2float(self.h[7])) * di + b2b.w;
        float4* op = (float4*)(out + (size_t)d * OUT_F + i * 8);
        op[0] = o0;
        op[1] = o1;
    }
}

// ---------------- launch: 6 dispatches ----------------

extern "C" void kernel_launch(void* const* d_in, const int* in_sizes, int n_in,
                              void* d_out, int out_size, void* d_ws, size_t ws_size,
                              hipStream_t stream) {
    const float* x     = (const float*)d_in[0];
    const int*   ei    = (const int*)d_in[1];
    const float* W1    = (const float*)d_in[2];
    const float* b1    = (const float*)d_in[3];
    const float* gamma = (const float*)d_in[4];
    const float* beta  = (const float*)d_in[5];
    const float* W2    = (const float*)d_in[6];
    const float* b2    = (const float*)d_in[7];
    float* out = (float*)d_out;

    char* ws = (char*)d_ws;
    int*            blkcnt = (int*)           (ws + 0);          //   153,664 B
    int*            rowptr = (int*)           (ws + 154624);     //   200,004 B
    float*          dinv   = (float*)         (ws + 356352);     //   200,000 B
    float*          st2    = (float*)         (ws + 558080);     //    16,384 B
    unsigned int*   bket   = (unsigned int*)  (ws + 574464);     // 3,200,000 B
    unsigned short* ssrc   = (unsigned short*)(ws + 3785728);    // 1,600,000 B
    __half*         h1s    = (__half*)        (ws + 5387264);    // 6,400,000 B
    __half*         agg1h  = (__half*)        (ws + 11787264);   // 6,400,000 B
    __half*         h2p    = (__half*)        (ws + 18187264);   // 6,400,000 B (padded 64)
    // total ~24.6 MB

    k_binscatter<<<NBLK, 512, 0, stream>>>(ei, blkcnt, bket, st2);
    k_bucket<<<NBK, 512, 0, stream>>>(blkcnt, bket, rowptr, dinv, ssrc);
    k_gemm1<<<NB_MM, 256, 0, stream>>>(x, W1, dinv, h1s);
    k_agg1<<<N_NODES / 4, 256, 0, stream>>>(rowptr, ssrc, dinv, h1s, b1, agg1h, st2);
    k_gemm2<<<NB_MM, 256, 0, stream>>>(agg1h, st2, gamma, beta, W2, dinv, h2p);
    k_agg2<<<N_NODES / 4, 256, 0, stream>>>(rowptr, ssrc, dinv, h2p, b2, out);
}

// Round 10
// 199.629 us; speedup vs baseline: 1.0531x; 1.0531x over previous
//
#include <hip/hip_runtime.h>
#include <hip/hip_fp16.h>

#define N_NODES 50000
#define N_EDGES 800000
#define IN_F    128
#define HID_F   64
#define OUT_F   40

#define EPB   4096                          // edges per sort block
#define NBLK  ((N_EDGES + EPB - 1) / EPB)   // 196 sort blocks
#define NBK   ((N_NODES + 255) / 256)       // 196 buckets (dst >> 8)
#define CAP   6144                          // per-bucket LDS cap (avg 4082, sd 64)
#define NREP  32                            // BN-stat atomic replicas
#define NB_MM ((N_NODES + 63) / 64)         // 782 gemm2 blocks (64 rows each)
#define NB_G1 ((N_NODES + 127) / 128)       // 391 gemm1 blocks (128 rows each)

typedef _Float16 half8v __attribute__((ext_vector_type(8)));
typedef float    f32x4  __attribute__((ext_vector_type(4)));

union h8cv { uint4 u; __half h[8]; };

// ============ dispatch 1: binscatter (blocks 0..195) || gemm1 (rest) ============
// gemm1 stores h1 UNSCALED (dinv doesn't exist yet); agg1 applies dinv[src].

__global__ __launch_bounds__(512) void k_pre(const int* __restrict__ ei,
                                             int* __restrict__ blkcnt,
                                             unsigned int* __restrict__ bket,
                                             float* __restrict__ st2,
                                             const float* __restrict__ x,
                                             const float* __restrict__ W1,
                                             __half* __restrict__ h1r) {
    __shared__ uint4 smem4[3328];          // 53248 B shared pool (both roles)
    __shared__ int h[256], fill[256], sc[256];
    int t = threadIdx.x;

    if (blockIdx.x < NBLK) {
        // ---------------- binscatter role ----------------
        unsigned int* staged = (unsigned int*)smem4;   // 16 KB
        if (t < 256) h[t] = 0;
        if (blockIdx.x == 0)               // zero BN-stat replicas once
            for (int i = t; i < NREP * 2 * HID_F; i += 512) st2[i] = 0.f;
        __syncthreads();
        int base = blockIdx.x * EPB;
        int nedge = N_EDGES - base; if (nedge > EPB) nedge = EPB;
#pragma unroll
        for (int it = 0; it < EPB / 512; ++it) {
            int e = base + it * 512 + t;
            if (e < N_EDGES) atomicAdd(&h[ei[N_EDGES + e] >> 8], 1);
        }
        __syncthreads();
        int v = (t < 256) ? h[t] : 0;
        if (t < 256) sc[t] = v;
        __syncthreads();
#pragma unroll
        for (int o = 1; o < 256; o <<= 1) {
            int u = (t < 256 && t >= o) ? sc[t - o] : 0;
            __syncthreads();
            if (t < 256) sc[t] += u;
            __syncthreads();
        }
        if (t < 256) fill[t] = sc[t] - v;  // exclusive
        __syncthreads();
#pragma unroll
        for (int it = 0; it < EPB / 512; ++it) {
            int e = base + it * 512 + t;
            if (e < N_EDGES) {
                int srcv = ei[e], dstv = ei[N_EDGES + e];
                int p = atomicAdd(&fill[dstv >> 8], 1);
                staged[p] = ((unsigned int)dstv << 16) | (unsigned int)srcv;
            }
        }
        __syncthreads();
        for (int i = t; i < nedge; i += 512) bket[base + i] = staged[i];
        if (t < NBK) blkcnt[t * NBLK + blockIdx.x] = h[t];
        return;
    }

    // ---------------- gemm1 role: 128 rows, MFMA 16x16x32 f16 ----------------
    _Float16 (*sA)[IN_F + 8] = (_Float16(*)[IN_F + 8])smem4;                    // 34816 B
    _Float16 (*sB)[IN_F + 8] = (_Float16(*)[IN_F + 8])((char*)smem4 + 34816);   // 17408 B
    int bid = blockIdx.x - NBLK;
    int row0 = bid * 128;
    for (int i = t; i < 128 * 32; i += 512) {
        int r  = i >> 5;
        int c4 = i & 31;
        int gr = row0 + r;
        float4 v = make_float4(0.f, 0.f, 0.f, 0.f);
        if (gr < N_NODES) v = ((const float4*)x)[gr * 32 + c4];
        sA[r][c4 * 4 + 0] = (_Float16)v.x;
        sA[r][c4 * 4 + 1] = (_Float16)v.y;
        sA[r][c4 * 4 + 2] = (_Float16)v.z;
        sA[r][c4 * 4 + 3] = (_Float16)v.w;
    }
    for (int i = t; i < IN_F * HID_F; i += 512) {
        int k = i >> 6, n = i & 63;
        sB[n][k] = (_Float16)W1[i];
    }
    __syncthreads();

    int lane = t & 63, wid = t >> 6;       // wid 0..7 -> 16 rows each
    int quad = lane >> 4, l15 = lane & 15;
    int m0 = wid * 16;
    half8v af[4];
#pragma unroll
    for (int ks = 0; ks < 4; ++ks)
        af[ks] = *(const half8v*)&sA[m0 + l15][ks * 32 + quad * 8];
    f32x4 acc[4];
#pragma unroll
    for (int nt = 0; nt < 4; ++nt) acc[nt] = (f32x4)(0.f);
#pragma unroll
    for (int nt = 0; nt < 4; ++nt) {
#pragma unroll
        for (int ks = 0; ks < 4; ++ks) {
            half8v bf = *(const half8v*)&sB[nt * 16 + l15][ks * 32 + quad * 8];
            acc[nt] = __builtin_amdgcn_mfma_f32_16x16x32_f16(af[ks], bf, acc[nt], 0, 0, 0);
        }
    }
    int rbase = row0 + m0 + quad * 4;
#pragma unroll
    for (int nt = 0; nt < 4; ++nt) {
        int col = nt * 16 + l15;
#pragma unroll
        for (int r = 0; r < 4; ++r) {
            int gr = rbase + r;
            if (gr < N_NODES)
                h1r[gr * HID_F + col] = __float2half(acc[nt][r]);   // unscaled
        }
    }
}

// ============ dispatch 2: per-bucket CSR build (scans in-kernel) ============

__global__ __launch_bounds__(512) void k_bucket(const int* __restrict__ blkcnt,
                                                const unsigned int* __restrict__ bket,
                                                int* __restrict__ rowptr,
                                                float* __restrict__ dinv,
                                                unsigned short* __restrict__ ssrc) {
    __shared__ unsigned int keys[CAP];     // 24 KB
    __shared__ unsigned short outb[CAP];   // 12 KB
    __shared__ int colpre[256], rowcnt[256], boffs[256];
    __shared__ int cnt[256], loc[256], fillb[256], sc[256];
    __shared__ int wsum[8], sbase, ssize;
    int b = blockIdx.x, t = threadIdx.x;
    int lane = t & 63, wid = t >> 6;

    int cp = 0, rc = 0;
    if (t < NBLK) {
        for (int bp = 0; bp < b; ++bp) cp += blkcnt[bp * NBLK + t];   // coalesced
        rc = blkcnt[b * NBLK + t];
    }
    if (t < 256) { colpre[t] = cp; rowcnt[t] = rc; }
    int red = cp;
#pragma unroll
    for (int o = 32; o > 0; o >>= 1) red += __shfl_down(red, o);
    if (lane == 0) wsum[wid] = red;
    __syncthreads();
    if (t == 0) {
        int s = 0;
#pragma unroll
        for (int r = 0; r < 8; ++r) s += wsum[r];
        sbase = s;
    }
    if (t < 256) sc[t] = rc;
    __syncthreads();
#pragma unroll
    for (int o = 1; o < 256; o <<= 1) {
        int u = (t < 256 && t >= o) ? sc[t - o] : 0;
        __syncthreads();
        if (t < 256) sc[t] += u;
        __syncthreads();
    }
    if (t < 256) boffs[t] = sc[t] - rc;
    if (t == 255) ssize = sc[255];
    __syncthreads();
    int base = sbase, size = ssize;

    for (int jj = wid; jj < NBLK; jj += 8) {
        int len = rowcnt[jj];
        int gs  = jj * EPB + colpre[jj];
        int d0  = boffs[jj];
        for (int o = lane; o < len; o += 64) keys[d0 + o] = bket[gs + o];
    }
    if (t < 256) cnt[t] = 0;
    __syncthreads();

    for (int i = t; i < size; i += 512) atomicAdd(&cnt[(keys[i] >> 16) & 255], 1);
    __syncthreads();
    int cv = (t < 256) ? cnt[t] : 0;
    if (t < 256) sc[t] = cv;
    __syncthreads();
#pragma unroll
    for (int o = 1; o < 256; o <<= 1) {
        int u = (t < 256 && t >= o) ? sc[t - o] : 0;
        __syncthreads();
        if (t < 256) sc[t] += u;
        __syncthreads();
    }
    if (t < 256) { loc[t] = sc[t] - cv; fillb[t] = sc[t] - cv; }
    int node = b * 256 + t;
    if (t < 256 && node < N_NODES) {
        rowptr[node] = base + loc[t];
        dinv[node]   = rsqrtf((float)cv + 1.0f);   // + self-loop
    }
    if (b == 0 && t == 0) rowptr[N_NODES] = N_EDGES;
    __syncthreads();

    for (int i = t; i < size; i += 512) {
        unsigned int k = keys[i];
        int p = atomicAdd(&fillb[(k >> 16) & 255], 1);
        outb[p] = (unsigned short)(k & 0xFFFFu);
    }
    __syncthreads();
    for (int i = t; i < size; i += 512) ssrc[base + i] = outb[i];
}

// ============ dispatch 3: layer-1 aggregation + fused BN statistics ============
// 8 groups x 8 lanes, uint4 gathers; per-edge dinv[src] (L2-hot broadcast).

__global__ __launch_bounds__(256) void k_agg1(const int* __restrict__ rowptr,
                                              const unsigned short* __restrict__ ssrc,
                                              const float* __restrict__ dinv,
                                              const __half* __restrict__ h1r,
                                              const float* __restrict__ b1,
                                              __half* __restrict__ agg1h,
                                              float* __restrict__ st2) {
    int lane = threadIdx.x & 63;
    int rloc = threadIdx.x >> 6;
    int g = lane >> 3, i = lane & 7;
    int d = blockIdx.x * 4 + rloc;
    int base = rowptr[d];
    int end  = rowptr[d + 1];
    float acc[8];
#pragma unroll
    for (int c = 0; c < 8; ++c) acc[c] = 0.f;
    for (int j0 = base; j0 < end; j0 += 64) {
        int idx = j0 + lane;
        int sl = (idx < end) ? (int)ssrc[idx] : 0;
        int m = end - j0; if (m > 64) m = 64;
        for (int c0 = 0; c0 < m; c0 += 32) {
            uint4 v[4]; float w[4];
#pragma unroll
            for (int k = 0; k < 4; ++k) {
                int j  = c0 + k * 8 + g;
                int jj = (j < m) ? j : (m - 1);
                int s  = __shfl(sl, jj);
                v[k] = ((const uint4*)(h1r + (size_t)s * HID_F))[i];
                w[k] = dinv[s];
            }
#pragma unroll
            for (int k = 0; k < 4; ++k) {
                float wk = ((c0 + k * 8 + g) < m) ? w[k] : 0.f;
                h8cv cv; cv.u = v[k];
#pragma unroll
                for (int c = 0; c < 8; ++c)
                    acc[c] += wk * __half2float(cv.h[c]);
            }
        }
    }
#pragma unroll
    for (int c = 0; c < 8; ++c) {
        acc[c] += __shfl_xor(acc[c], 8);
        acc[c] += __shfl_xor(acc[c], 16);
        acc[c] += __shfl_xor(acc[c], 32);
    }
    h8cv self; self.u = ((const uint4*)(h1r + (size_t)d * HID_F))[i];
    float di = dinv[d];
    float val[8];
#pragma unroll
    for (int c = 0; c < 8; ++c)
        val[c] = (acc[c] + di * __half2float(self.h[c])) * di + b1[i * 8 + c];
    if (g == 0) {
        h8cv ov;
#pragma unroll
        for (int c = 0; c < 8; ++c) ov.h[c] = __float2half(val[c]);
        ((uint4*)(agg1h + (size_t)d * HID_F))[i] = ov.u;
    }
    __shared__ float ls[4][HID_F], ls2[4][HID_F];
    if (g == 0) {
#pragma unroll
        for (int c = 0; c < 8; ++c) {
            ls[rloc][i * 8 + c]  = val[c];
            ls2[rloc][i * 8 + c] = val[c] * val[c];
        }
    }
    __syncthreads();
    if (rloc == 0) {
        float sm = ls[0][lane] + ls[1][lane] + ls[2][lane] + ls[3][lane];
        float s2 = ls2[0][lane] + ls2[1][lane] + ls2[2][lane] + ls2[3][lane];
        float* strow = st2 + (blockIdx.x & (NREP - 1)) * (2 * HID_F);
        atomicAdd(&strow[lane], sm);
        atomicAdd(&strow[HID_F + lane], s2);
    }
}

// ============ dispatch 4: GEMM2 (MFMA), h2p[N,64] pre-scaled by dinv ============

__global__ __launch_bounds__(256) void k_gemm2(const __half* __restrict__ agg1h,
                                               const float* __restrict__ st2,
                                               const float* __restrict__ gamma,
                                               const float* __restrict__ beta,
                                               const float* __restrict__ W2,
                                               const float* __restrict__ dinv,
                                               __half* __restrict__ h2p) {
    __shared__ _Float16 sA[64][HID_F + 8];   // 9216 B
    __shared__ _Float16 sB[48][HID_F + 8];   // 6912 B  (sB[n][k] = W2[k][n], pad n>=40)
    __shared__ float sScale[HID_F], sShift[HID_F];
    int t = threadIdx.x;
    if (t < HID_F) {
        float sm = 0.f, s2 = 0.f;
#pragma unroll
        for (int r = 0; r < NREP; ++r) {
            sm += st2[r * (2 * HID_F) + t];
            s2 += st2[r * (2 * HID_F) + HID_F + t];
        }
        float mean = sm * (1.0f / N_NODES);
        float var  = s2 * (1.0f / N_NODES) - mean * mean;
        float inv  = rsqrtf(var + 1e-5f);
        float gv   = gamma[t];
        sScale[t]  = gv * inv;
        sShift[t]  = beta[t] - gv * inv * mean;
    }
    for (int i = t; i < 48 * HID_F; i += 256) {
        int k = i / 48, n = i - k * 48;
        sB[n][k] = (n < OUT_F) ? (_Float16)W2[k * OUT_F + n] : (_Float16)0.f;
    }
    __syncthreads();
    int row0 = blockIdx.x * 64;
    for (int i = t; i < 64 * HID_F; i += 256) {
        int r = i >> 6, k = i & 63;
        int gr = row0 + r;
        float v = 0.f;
        if (gr < N_NODES) {
            float a = __half2float(agg1h[gr * HID_F + k]);
            v = fmaxf(a * sScale[k] + sShift[k], 0.f);
        }
        sA[r][k] = (_Float16)v;
    }
    __syncthreads();

    int lane = t & 63, wid = t >> 6;
    int quad = lane >> 4, l15 = lane & 15;
    int m0 = wid * 16;
    half8v af[2];
#pragma unroll
    for (int ks = 0; ks < 2; ++ks)
        af[ks] = *(const half8v*)&sA[m0 + l15][ks * 32 + quad * 8];
    f32x4 acc[3];
#pragma unroll
    for (int nt = 0; nt < 3; ++nt) acc[nt] = (f32x4)(0.f);
#pragma unroll
    for (int nt = 0; nt < 3; ++nt) {
#pragma unroll
        for (int ks = 0; ks < 2; ++ks) {
            half8v bf = *(const half8v*)&sB[nt * 16 + l15][ks * 32 + quad * 8];
            acc[nt] = __builtin_amdgcn_mfma_f32_16x16x32_f16(af[ks], bf, acc[nt], 0, 0, 0);
        }
    }
    float dv[4];
    int rbase = row0 + m0 + quad * 4;
#pragma unroll
    for (int r = 0; r < 4; ++r)
        dv[r] = (rbase + r < N_NODES) ? dinv[rbase + r] : 0.f;
#pragma unroll
    for (int nt = 0; nt < 3; ++nt) {
        int col = nt * 16 + l15;
#pragma unroll
        for (int r = 0; r < 4; ++r) {
            int gr = rbase + r;
            if (gr < N_NODES)
                h2p[(size_t)gr * 64 + col] = __float2half(acc[nt][r] * dv[r]);
        }
    }
#pragma unroll
    for (int r = 0; r < 4; ++r) {          // zero pad cols 48..63
        int gr = rbase + r;
        if (gr < N_NODES) h2p[(size_t)gr * 64 + 48 + l15] = __float2half(0.f);
    }
}

// ============ dispatch 5: layer-2 aggregation -> d_out ============

__global__ __launch_bounds__(256) void k_agg2(const int* __restrict__ rowptr,
                                              const unsigned short* __restrict__ ssrc,
                                              const float* __restrict__ dinv,
                                              const __half* __restrict__ h2p,
                                              const float* __restrict__ b2,
                                              float* __restrict__ out) {
    int lane = threadIdx.x & 63;
    int rloc = threadIdx.x >> 6;
    int g = lane >> 3, i = lane & 7;
    int d = blockIdx.x * 4 + rloc;
    int base = rowptr[d];
    int end  = rowptr[d + 1];
    float acc[8];
#pragma unroll
    for (int c = 0; c < 8; ++c) acc[c] = 0.f;
    for (int j0 = base; j0 < end; j0 += 64) {
        int idx = j0 + lane;
        int sl = (idx < end) ? (int)ssrc[idx] : 0;
        int m = end - j0; if (m > 64) m = 64;
        for (int c0 = 0; c0 < m; c0 += 32) {
            uint4 v[4];
#pragma unroll
            for (int k = 0; k < 4; ++k) {
                int j  = c0 + k * 8 + g;
                int jj = (j < m) ? j : (m - 1);
                int s  = __shfl(sl, jj);
                v[k] = ((const uint4*)(h2p + (size_t)s * 64))[i];
            }
#pragma unroll
            for (int k = 0; k < 4; ++k) {
                bool ok = (c0 + k * 8 + g) < m;
                h8cv cv; cv.u = v[k];
#pragma unroll
                for (int c = 0; c < 8; ++c)
                    acc[c] += ok ? __half2float(cv.h[c]) : 0.f;
            }
        }
    }
#pragma unroll
    for (int c = 0; c < 8; ++c) {
        acc[c] += __shfl_xor(acc[c], 8);
        acc[c] += __shfl_xor(acc[c], 16);
        acc[c] += __shfl_xor(acc[c], 32);
    }
    if (g == 0 && i < 5) {                 // cols i*8 .. i*8+7 (<40)
        h8cv self; self.u = ((const uint4*)(h2p + (size_t)d * 64))[i];
        float di = dinv[d];
        const float4 b2a = ((const float4*)b2)[i * 2];
        const float4 b2b = ((const float4*)b2)[i * 2 + 1];
        float4 o0, o1;
        o0.x = (acc[0] + __half2float(self.h[0])) * di + b2a.x;
        o0.y = (acc[1] + __half2float(self.h[1])) * di + b2a.y;
        o0.z = (acc[2] + __half2float(self.h[2])) * di + b2a.z;
        o0.w = (acc[3] + __half2float(self.h[3])) * di + b2a.w;
        o1.x = (acc[4] + __half2float(self.h[4])) * di + b2b.x;
        o1.y = (acc[5] + __half2float(self.h[5])) * di + b2b.y;
        o1.z = (acc[6] + __half2float(self.h[6])) * di + b2b.z;
        o1.w = (acc[7] + __half2float(self.h[7])) * di + b2b.w;
        float4* op = (float4*)(out + (size_t)d * OUT_F + i * 8);
        op[0] = o0;
        op[1] = o1;
    }
}

// ---------------- launch: 5 dispatches ----------------

extern "C" void kernel_launch(void* const* d_in, const int* in_sizes, int n_in,
                              void* d_out, int out_size, void* d_ws, size_t ws_size,
                              hipStream_t stream) {
    const float* x     = (const float*)d_in[0];
    const int*   ei    = (const int*)d_in[1];
    const float* W1    = (const float*)d_in[2];
    const float* b1    = (const float*)d_in[3];
    const float* gamma = (const float*)d_in[4];
    const float* beta  = (const float*)d_in[5];
    const float* W2    = (const float*)d_in[6];
    const float* b2    = (const float*)d_in[7];
    float* out = (float*)d_out;

    char* ws = (char*)d_ws;
    int*            blkcnt = (int*)           (ws + 0);          //   153,664 B
    int*            rowptr = (int*)           (ws + 154624);     //   200,004 B
    float*          dinv   = (float*)         (ws + 356352);     //   200,000 B
    float*          st2    = (float*)         (ws + 558080);     //    16,384 B
    unsigned int*   bket   = (unsigned int*)  (ws + 574464);     // 3,200,000 B
    unsigned short* ssrc   = (unsigned short*)(ws + 3785728);    // 1,600,000 B
    __half*         h1r    = (__half*)        (ws + 5387264);    // 6,400,000 B (unscaled)
    __half*         agg1h  = (__half*)        (ws + 11787264);   // 6,400,000 B
    __half*         h2p    = (__half*)        (ws + 18187264);   // 6,400,000 B (padded 64)
    // total ~24.6 MB

    k_pre<<<NBLK + NB_G1, 512, 0, stream>>>(ei, blkcnt, bket, st2, x, W1, h1r);
    k_bucket<<<NBK, 512, 0, stream>>>(blkcnt, bket, rowptr, dinv, ssrc);
    k_agg1<<<N_NODES / 4, 256, 0, stream>>>(rowptr, ssrc, dinv, h1r, b1, agg1h, st2);
    k_gemm2<<<NB_MM, 256, 0, stream>>>(agg1h, st2, gamma, beta, W2, dinv, h2p);
    k_agg2<<<N_NODES / 4, 256, 0, stream>>>(rowptr, ssrc, dinv, h2p, b2, out);
}